// Round 7
// baseline (403.345 us; speedup 1.0000x reference)
//
#include <hip/hip_runtime.h>
#include <hip/hip_bf16.h>

// Problem constants (fixed by the reference)
#define BB 4
#define TT 1024
#define DD 1024
#define HH 16
#define HDIM 64
#define MM (BB*TT)          // 4096

typedef unsigned short u16;
typedef __attribute__((ext_vector_type(8))) short bf16x8;   // 8 bf16 = 4 VGPRs
typedef __attribute__((ext_vector_type(4))) float f32x4;
typedef __attribute__((ext_vector_type(4))) unsigned short u16x4;

__device__ __forceinline__ u16 f2bf(float f) {
    union { float f; unsigned u; } v; v.f = f;
    return (u16)((v.u + 0x7fffu + ((v.u >> 16) & 1u)) >> 16);   // RNE
}
__device__ __forceinline__ float bf2f(u16 h) {
    union { unsigned u; float f; } v; v.u = ((unsigned)h) << 16; return v.f;
}

// async global->LDS, 16B per lane; lds dest = wave-uniform base + lane*16
__device__ __forceinline__ void gload16(const void* g, void* l) {
    __builtin_amdgcn_global_load_lds(
        (const __attribute__((address_space(1))) unsigned int*)g,
        (__attribute__((address_space(3))) unsigned int*)l, 16, 0, 0);
}

// src f32 -> hi = bf16(src), lo = bf16(src - hi)   (lo may be null)
__global__ __launch_bounds__(256)
void split_kernel(const float* __restrict__ src, u16* __restrict__ hi,
                  u16* __restrict__ lo)
{
    const size_t i = ((size_t)blockIdx.x * 256 + threadIdx.x) * 4;
    const float4 v = *(const float4*)&src[i];
    u16x4 h;
    h[0] = f2bf(v.x); h[1] = f2bf(v.y); h[2] = f2bf(v.z); h[3] = f2bf(v.w);
    *(u16x4*)&hi[i] = h;
    if (lo != nullptr) {
        u16x4 l;
        l[0] = f2bf(v.x - bf2f(h[0]));
        l[1] = f2bf(v.y - bf2f(h[1]));
        l[2] = f2bf(v.z - bf2f(h[2]));
        l[3] = f2bf(v.w - bf2f(h[3]));
        *(u16x4*)&lo[i] = l;
    }
}

// k16 [b][h][t][64] -> k16T [b][h][d][1024]   (per-head 64-col transpose)
__global__ __launch_bounds__(256)
void ktrans_kernel(const u16* __restrict__ k16, u16* __restrict__ k16T)
{
    __shared__ u16 tmp[64][72];
    const int tc = blockIdx.x, h = blockIdx.y, b = blockIdx.z;
    const size_t hb = ((size_t)(b * HH + h)) << 16;
    const int tid = threadIdx.x;
    const int sr = tid >> 2, sc = (tid & 3) * 8;
    *(bf16x8*)&tmp[sr][sc]      = *(const bf16x8*)&k16[hb + (size_t)(tc * 64 + sr) * HDIM + sc];
    *(bf16x8*)&tmp[sr][sc + 32] = *(const bf16x8*)&k16[hb + (size_t)(tc * 64 + sr) * HDIM + sc + 32];
    __syncthreads();
#pragma unroll
    for (int half = 0; half < 2; ++half) {
        bf16x8 v;
#pragma unroll
        for (int j = 0; j < 8; ++j) v[j] = (short)tmp[sc + half * 32 + j][sr];
        *(bf16x8*)&k16T[hb + (size_t)sr * TT + tc * 64 + sc + half * 32] = v;
    }
}

// ---------------------------------------------------------------------------
// MFMA GEMM: C = A @ B^T + bias (unchanged from round 3).
// ---------------------------------------------------------------------------
template<bool SPLIT, int MODE>
__global__ __launch_bounds__(256)
void gemm_mfma(const u16* __restrict__ Ah, const u16* __restrict__ Al,
               const u16* __restrict__ Bh, const u16* __restrict__ Bl,
               const float* __restrict__ bias,
               float* __restrict__ dstF, u16* __restrict__ dstH1,
               u16* __restrict__ dstH2, const float* __restrict__ kaux,
               const int M, const int N, const int K)
{
    __shared__ u16 As[128][64];
    __shared__ u16 Bs[128][64];
    __shared__ u16 As2[SPLIT ? 128 : 1][64];
    __shared__ u16 Bs2[SPLIT ? 128 : 1][64];

    const int tid  = threadIdx.x;
    const int w    = tid >> 6;
    const int lane = tid & 63;
    const int lg   = lane >> 4;
    const int lr   = lane & 15;
    const int wr   = w >> 1, wc = w & 1;
    const int m0   = blockIdx.y * 128, n0 = blockIdx.x * 128;

    const f32x4 zero = {0.f, 0.f, 0.f, 0.f};
    f32x4 acc[4][4];
#pragma unroll
    for (int i = 0; i < 4; ++i)
#pragma unroll
        for (int j = 0; j < 4; ++j) acc[i][j] = zero;

    const int srow = tid >> 3;
    const int scol = (tid & 7) * 8;
    const int ldr  = w << 3;

    for (int k0 = 0; k0 < K; k0 += 64) {
        __syncthreads();
#pragma unroll
        for (int i = 0; i < 4; ++i) {
            const size_t ga = (size_t)(m0 + i * 32 + srow) * K + k0 + scol;
            const size_t gb = (size_t)(n0 + i * 32 + srow) * K + k0 + scol;
            gload16(&Ah[ga], &As[i * 32 + ldr][0]);
            gload16(&Bh[gb], &Bs[i * 32 + ldr][0]);
            if constexpr (SPLIT) {
                gload16(&Al[ga], &As2[i * 32 + ldr][0]);
                gload16(&Bl[gb], &Bs2[i * 32 + ldr][0]);
            }
        }
        __syncthreads();
#pragma unroll
        for (int kk = 0; kk < 2; ++kk) {
            const int koff = kk * 32 + lg * 8;
            bf16x8 a_h[4], b_h[4];
#pragma unroll
            for (int f = 0; f < 4; ++f) {
                a_h[f] = *(const bf16x8*)&As[wr * 64 + f * 16 + lr][koff];
                b_h[f] = *(const bf16x8*)&Bs[wc * 64 + f * 16 + lr][koff];
            }
            if constexpr (SPLIT) {
                bf16x8 a_l[4], b_l[4];
#pragma unroll
                for (int f = 0; f < 4; ++f) {
                    a_l[f] = *(const bf16x8*)&As2[wr * 64 + f * 16 + lr][koff];
                    b_l[f] = *(const bf16x8*)&Bs2[wc * 64 + f * 16 + lr][koff];
                }
#pragma unroll
                for (int mf = 0; mf < 4; ++mf)
#pragma unroll
                    for (int nf = 0; nf < 4; ++nf) {
                        acc[mf][nf] = __builtin_amdgcn_mfma_f32_16x16x32_bf16(a_h[mf], b_h[nf], acc[mf][nf], 0, 0, 0);
                        acc[mf][nf] = __builtin_amdgcn_mfma_f32_16x16x32_bf16(a_l[mf], b_h[nf], acc[mf][nf], 0, 0, 0);
                        acc[mf][nf] = __builtin_amdgcn_mfma_f32_16x16x32_bf16(a_h[mf], b_l[nf], acc[mf][nf], 0, 0, 0);
                    }
            } else {
#pragma unroll
                for (int mf = 0; mf < 4; ++mf)
#pragma unroll
                    for (int nf = 0; nf < 4; ++nf)
                        acc[mf][nf] = __builtin_amdgcn_mfma_f32_16x16x32_bf16(a_h[mf], b_h[nf], acc[mf][nf], 0, 0, 0);
            }
        }
    }

#pragma unroll
    for (int mf = 0; mf < 4; ++mf)
#pragma unroll
        for (int nf = 0; nf < 4; ++nf)
#pragma unroll
            for (int j = 0; j < 4; ++j) {
                const int gm = m0 + wr * 64 + mf * 16 + lg * 4 + j;
                const int gn = n0 + wc * 64 + nf * 16 + lr;
                const float v = acc[mf][nf][j] + bias[gn];
                if constexpr (MODE == 0) {
                    const int bb = gm >> 10, t = gm & 1023;
                    const int c = gn >> 10, hh = (gn & 1023) >> 6, d = gn & 63;
                    const size_t idx = ((((size_t)bb * HH + hh) << 10) + t) * HDIM + d;
                    if (c == 0) dstH1[idx] = f2bf(v * 0.125f);
                    else { dstF[idx] = v; dstH2[idx] = f2bf(v); }
                } else if constexpr (MODE == 1) {
                    const int bb = gm >> 10, t = gm & 1023;
                    const int hh = gn >> 6, d = gn & 63;
                    const size_t idx = ((((size_t)bb * HH + hh) << 10) + t) * HDIM + d;
                    dstH1[idx] = f2bf(v + kaux[idx]);
                } else {
                    dstF[(size_t)gm * N + gn] = v;
                }
            }
}

// ---------------------------------------------------------------------------
// Fused attention v3: swapped-operand QK^T, QBLK=64, single exp, 1 block/CU.
// Sweep A (16 kv-tiles, dbuf): S = mfma(KP, Q) -> lane holds P[kv=4lg+j][q=lr]
//   i.e. all 16 values of a lane belong to q-row (w*16+lr). exp once, rowsum
//   accumulates per-lane, P -> bf16 -> P_s[64][1032] (wave-local rows).
// rowsum: 2x shfl_xor (lg dims) -> ri_s[64].
// Sweep B (16 kv-tiles, dbuf): attn tile write (normalized, nontemporal)
//   interleaved with PV mfma(P, K^T); ctx = cacc*ri -> bf16.
// Frag maps (verified): A/B row=lane&15, k=8*(lane>>4)+i; C/D col=lane&15,
//   row=4*(lane>>4)+reg.
// ---------------------------------------------------------------------------
__global__ __launch_bounds__(256)
void attn_fused(const u16* __restrict__ qg, const u16* __restrict__ kTg,
                const u16* __restrict__ kpg,
                float* __restrict__ attn, u16* __restrict__ ch)
{
    __shared__ u16 P_s[64][1032];       // unnormalized exp(S) bf16, 132 KB
    __shared__ u16 kv_s[2][64][72];     // kp (sweep A) / kT (sweep B), dbuf
    __shared__ float ri_s[64];

    const int tid  = threadIdx.x;
    const int w    = tid >> 6;          // wave 0..3 -> q rows w*16..w*16+15
    const int lane = tid & 63;
    const int lg   = lane >> 4;         // 0..3
    const int lr   = lane & 15;         // 0..15
    const int q0   = blockIdx.x * 64;
    const int h = blockIdx.y, b = blockIdx.z;
    const size_t hb = ((size_t)(b * HH + h)) << 16;   // head base (T*64)

    // Q fragments (B operand): row = lr -> q = q0 + w*16 + lr
    bf16x8 qf0, qf1;
    {
        const size_t base = hb + (size_t)(q0 + w * 16 + lr) * HDIM + lg * 8;
        qf0 = *(const bf16x8*)&qg[base];
        qf1 = *(const bf16x8*)&qg[base + 32];
    }

    // staging decomposition: thread -> (row sr, 16-col chunk sc)
    const int sr = tid >> 2;            // 0..63
    const int sc = (tid & 3) * 16;      // 0,16,32,48
    bf16x8 sa, sb;                      // staging registers

    // ---- sweep A: swapped QK^T + exp -> P_s, per-lane rowsum ----
    // prologue: stage kp tile 0
    sa = *(const bf16x8*)&kpg[hb + (size_t)sr * HDIM + sc];
    sb = *(const bf16x8*)&kpg[hb + (size_t)sr * HDIM + sc + 8];
    *(bf16x8*)&kv_s[0][sr][sc]     = sa;
    *(bf16x8*)&kv_s[0][sr][sc + 8] = sb;
    __syncthreads();

    float rs = 0.f;
    for (int t = 0; t < 16; ++t) {
        const int cur = t & 1;
        if (t < 15) {   // issue next tile's loads early (latency hides under MFMA)
            const size_t base = hb + (size_t)((t + 1) * 64 + sr) * HDIM + sc;
            sa = *(const bf16x8*)&kpg[base];
            sb = *(const bf16x8*)&kpg[base + 8];
        }
#pragma unroll
        for (int ct = 0; ct < 4; ++ct) {
            f32x4 acc = {0.f, 0.f, 0.f, 0.f};
            const bf16x8 a0 = *(const bf16x8*)&kv_s[cur][ct * 16 + lr][lg * 8];
            const bf16x8 a1 = *(const bf16x8*)&kv_s[cur][ct * 16 + lr][lg * 8 + 32];
            acc = __builtin_amdgcn_mfma_f32_16x16x32_bf16(a0, qf0, acc, 0, 0, 0);
            acc = __builtin_amdgcn_mfma_f32_16x16x32_bf16(a1, qf1, acc, 0, 0, 0);
            // lane: q = w*16+lr (fixed), kv = t*64 + ct*16 + 4*lg + j
            u16x4 pw;
#pragma unroll
            for (int j = 0; j < 4; ++j) {
                const float p = __expf(acc[j]);
                rs += p;
                pw[j] = f2bf(p);
            }
            *(u16x4*)&P_s[w * 16 + lr][t * 64 + ct * 16 + lg * 4] = pw;
        }
        if (t < 15) {   // vmcnt-wait implicit on sa/sb use; write other buffer
            *(bf16x8*)&kv_s[cur ^ 1][sr][sc]     = sa;
            *(bf16x8*)&kv_s[cur ^ 1][sr][sc + 8] = sb;
        }
        __syncthreads();
    }

    // ---- rowsum reduce + transition ----
    // issue kT tile 0 loads first (hide under reduce)
    sa = *(const bf16x8*)&kTg[hb + (size_t)sr * TT + sc];
    sb = *(const bf16x8*)&kTg[hb + (size_t)sr * TT + sc + 8];
    rs += __shfl_xor(rs, 16);
    rs += __shfl_xor(rs, 32);
    const float ri = 1.f / rs;          // normalizer for q-row w*16+lr
    if (lg == 0) ri_s[w * 16 + lr] = ri;
    *(bf16x8*)&kv_s[0][sr][sc]     = sa;
    *(bf16x8*)&kv_s[0][sr][sc + 8] = sb;
    __syncthreads();                    // ri_s + kT tile0 + P_s all visible

    // ---- sweep B: attn write (interleaved) + PV ----
    const size_t abase = ((((size_t)b * HH + h) << 10) + q0) << 10;
    f32x4 cacc[4] = {{0,0,0,0},{0,0,0,0},{0,0,0,0},{0,0,0,0}};

    for (int t = 0; t < 16; ++t) {
        const int cur = t & 1;
        if (t < 15) {
            const size_t base = hb + (size_t)sr * TT + (t + 1) * 64 + sc;
            sa = *(const bf16x8*)&kTg[base];
            sb = *(const bf16x8*)&kTg[base + 8];
        }
        // attn output for this tile's 64 cols (all 64 rows), normalized
        {
            const float rv = ri_s[sr];
            const bf16x8 p0 = *(const bf16x8*)&P_s[sr][t * 64 + sc];
            const bf16x8 p1 = *(const bf16x8*)&P_s[sr][t * 64 + sc + 8];
            float* dst = &attn[abase + (size_t)sr * TT + t * 64 + sc];
            f32x4 o0, o1, o2, o3;
#pragma unroll
            for (int j = 0; j < 4; ++j) {
                o0[j] = bf2f((u16)p0[j]) * rv;
                o1[j] = bf2f((u16)p0[j + 4]) * rv;
                o2[j] = bf2f((u16)p1[j]) * rv;
                o3[j] = bf2f((u16)p1[j + 4]) * rv;
            }
            __builtin_nontemporal_store(o0, (f32x4*)dst);
            __builtin_nontemporal_store(o1, (f32x4*)(dst + 4));
            __builtin_nontemporal_store(o2, (f32x4*)(dst + 8));
            __builtin_nontemporal_store(o3, (f32x4*)(dst + 12));
        }
        // PV: A = P_s rows (wave-local), B = kT rows (d = dt*16+lr)
        const bf16x8 pa0 = *(const bf16x8*)&P_s[w * 16 + lr][t * 64 + lg * 8];
        const bf16x8 pa1 = *(const bf16x8*)&P_s[w * 16 + lr][t * 64 + 32 + lg * 8];
#pragma unroll
        for (int dt = 0; dt < 4; ++dt) {
            const bf16x8 kb0 = *(const bf16x8*)&kv_s[cur][dt * 16 + lr][lg * 8];
            const bf16x8 kb1 = *(const bf16x8*)&kv_s[cur][dt * 16 + lr][lg * 8 + 32];
            cacc[dt] = __builtin_amdgcn_mfma_f32_16x16x32_bf16(pa0, kb0, cacc[dt], 0, 0, 0);
            cacc[dt] = __builtin_amdgcn_mfma_f32_16x16x32_bf16(pa1, kb1, cacc[dt], 0, 0, 0);
        }
        if (t < 15) {
            *(bf16x8*)&kv_s[cur ^ 1][sr][sc]     = sa;
            *(bf16x8*)&kv_s[cur ^ 1][sr][sc + 8] = sb;
        }
        __syncthreads();
    }

    // ctx -> bf16 [B][T][H*64]: lane -> q = q0+w*16+4lg+j, d = dt*16+lr
#pragma unroll
    for (int j = 0; j < 4; ++j) {
        const float rj = ri_s[w * 16 + lg * 4 + j];
        const int qr = q0 + w * 16 + lg * 4 + j;
#pragma unroll
        for (int dt = 0; dt < 4; ++dt)
            ch[(((size_t)b << 10) + qr) * DD + h * HDIM + dt * 16 + lr] =
                f2bf(cacc[dt][j] * rj);
    }
}

extern "C" void kernel_launch(void* const* d_in, const int* in_sizes, int n_in,
                              void* d_out, int out_size, void* d_ws, size_t ws_size,
                              hipStream_t stream)
{
    const float* x  = (const float*)d_in[0];
    const float* pe = (const float*)d_in[1];
    const float* Wc = (const float*)d_in[2];
    const float* bc = (const float*)d_in[3];
    const float* Wp = (const float*)d_in[4];
    const float* bp = (const float*)d_in[5];
    const float* Wo = (const float*)d_in[6];
    const float* bo = (const float*)d_in[7];

    float* out  = (float*)d_out;                         // [B][T][D]
    float* attn = out + (size_t)MM * DD;                 // [B][H][T][T]

    // 64 MB workspace layout (in-order stream => safe region reuse)
    char* ws = (char*)d_ws;
    float* kf32 = (float*)(ws);                          // [0,16M)   k fp32
    u16* q16  = (u16*)(ws + ((size_t)16 << 20));         // [16,24M)
    u16* k16  = (u16*)(ws + ((size_t)24 << 20));         // [24,32M)
    u16* kp16 = (u16*)(ws + ((size_t)32 << 20));         // [32,40M)
    u16* k16T = (u16*)(ws + ((size_t)56 << 20));         // [56,64M)  k transposed
    u16* xh  = (u16*)(ws + ((size_t)40 << 20));          // 8MB
    u16* xl  = (u16*)(ws + ((size_t)48 << 20));          // 8MB
    u16* Wch = (u16*)(ws + ((size_t)56 << 20));          // 4MB (k16T area, dead before ktrans)
    u16* Wcl = (u16*)(ws + ((size_t)60 << 20));          // 4MB
    u16* peh = xh, *pel = xl;                            // after cqk
    u16* Wph = (u16*)(ws + ((size_t)24 << 20));          // k16 area, dead after ktrans
    u16* Wpl = (u16*)(ws + ((size_t)26 << 20));
    u16* chh = xh;                                       // ctx bf16, after pk
    u16* Woh = (u16*)(ws + ((size_t)48 << 20));          // 2MB (xl dead)

    // 1) splits for cqk
    split_kernel<<<4096, 256, 0, stream>>>(x, xh, xl);
    split_kernel<<<2048, 256, 0, stream>>>(Wc, Wch, Wcl);
    // 2) cqk = x @ Wc^T + bc -> q16 (scaled), kf32, k16
    gemm_mfma<true, 0><<<dim3(16, 32), 256, 0, stream>>>(
        xh, xl, Wch, Wcl, bc, kf32, q16, k16, nullptr, MM, 2048, DD);
    // 3) k16T = transpose(k16)  (overwrites Wc split -- dead after gemm)
    ktrans_kernel<<<dim3(16, HH, BB), 256, 0, stream>>>(k16, k16T);
    // 4) splits for pk (Wp split into k16's region -- k16 dead after ktrans)
    split_kernel<<<4096, 256, 0, stream>>>(pe, peh, pel);
    split_kernel<<<1024, 256, 0, stream>>>(Wp, Wph, Wpl);
    // 5) pk = pe @ Wp^T + bp; kp16 = bf16(pk + k)
    gemm_mfma<true, 1><<<dim3(8, 32), 256, 0, stream>>>(
        peh, pel, Wph, Wpl, bp, nullptr, kp16, nullptr, kf32, MM, 1024, DD);
    // 6) attention: attn f32 + ctx bf16
    attn_fused<<<dim3(TT / 64, HH, BB), 256, 0, stream>>>(
        q16, k16T, kp16, attn, chh);
    // 7) split Wo (hi only), out = ctx @ Wo^T + bo
    split_kernel<<<1024, 256, 0, stream>>>(Wo, Woh, nullptr);
    gemm_mfma<false, 2><<<dim3(8, 32), 256, 0, stream>>>(
        chh, nullptr, Woh, nullptr, bo, out, nullptr, nullptr, nullptr, MM, 1024, DD);
}

// Round 8
// 250.178 us; speedup vs baseline: 1.6122x; 1.6122x over previous
//
#include <hip/hip_runtime.h>
#include <hip/hip_bf16.h>

// Problem constants (fixed by the reference)
#define BB 4
#define TT 1024
#define DD 1024
#define HH 16
#define HDIM 64
#define MM (BB*TT)          // 4096

typedef unsigned short u16;
typedef __attribute__((ext_vector_type(8))) short bf16x8;   // 8 bf16 = 4 VGPRs
typedef __attribute__((ext_vector_type(4))) float f32x4;
typedef __attribute__((ext_vector_type(4))) unsigned short u16x4;

__device__ __forceinline__ u16 f2bf(float f) {
    union { float f; unsigned u; } v; v.f = f;
    return (u16)((v.u + 0x7fffu + ((v.u >> 16) & 1u)) >> 16);   // RNE
}
__device__ __forceinline__ float bf2f(u16 h) {
    union { unsigned u; float f; } v; v.u = ((unsigned)h) << 16; return v.f;
}

// async global->LDS, 16B per lane; lds dest = wave-uniform base + lane*16
__device__ __forceinline__ void gload16(const void* g, void* l) {
    __builtin_amdgcn_global_load_lds(
        (const __attribute__((address_space(1))) unsigned int*)g,
        (__attribute__((address_space(3))) unsigned int*)l, 16, 0, 0);
}

// src f32 -> hi = bf16(src), lo = bf16(src - hi)   (lo may be null)
__global__ __launch_bounds__(256)
void split_kernel(const float* __restrict__ src, u16* __restrict__ hi,
                  u16* __restrict__ lo)
{
    const size_t i = ((size_t)blockIdx.x * 256 + threadIdx.x) * 4;
    const float4 v = *(const float4*)&src[i];
    u16x4 h;
    h[0] = f2bf(v.x); h[1] = f2bf(v.y); h[2] = f2bf(v.z); h[3] = f2bf(v.w);
    *(u16x4*)&hi[i] = h;
    if (lo != nullptr) {
        u16x4 l;
        l[0] = f2bf(v.x - bf2f(h[0]));
        l[1] = f2bf(v.y - bf2f(h[1]));
        l[2] = f2bf(v.z - bf2f(h[2]));
        l[3] = f2bf(v.w - bf2f(h[3]));
        *(u16x4*)&lo[i] = l;
    }
}

// k16 [b][h][t][64] -> k16T [b][h][d][1024]   (per-head 64-col transpose)
__global__ __launch_bounds__(256)
void ktrans_kernel(const u16* __restrict__ k16, u16* __restrict__ k16T)
{
    __shared__ u16 tmp[64][72];
    const int tc = blockIdx.x, h = blockIdx.y, b = blockIdx.z;
    const size_t hb = ((size_t)(b * HH + h)) << 16;
    const int tid = threadIdx.x;
    const int sr = tid >> 2, sc = (tid & 3) * 8;
    *(bf16x8*)&tmp[sr][sc]      = *(const bf16x8*)&k16[hb + (size_t)(tc * 64 + sr) * HDIM + sc];
    *(bf16x8*)&tmp[sr][sc + 32] = *(const bf16x8*)&k16[hb + (size_t)(tc * 64 + sr) * HDIM + sc + 32];
    __syncthreads();
#pragma unroll
    for (int half = 0; half < 2; ++half) {
        bf16x8 v;
#pragma unroll
        for (int j = 0; j < 8; ++j) v[j] = (short)tmp[sc + half * 32 + j][sr];
        *(bf16x8*)&k16T[hb + (size_t)sr * TT + tc * 64 + sc + half * 32] = v;
    }
}

// ---------------------------------------------------------------------------
// MFMA GEMM: C = A @ B^T + bias (unchanged from round 3).
// ---------------------------------------------------------------------------
template<bool SPLIT, int MODE>
__global__ __launch_bounds__(256)
void gemm_mfma(const u16* __restrict__ Ah, const u16* __restrict__ Al,
               const u16* __restrict__ Bh, const u16* __restrict__ Bl,
               const float* __restrict__ bias,
               float* __restrict__ dstF, u16* __restrict__ dstH1,
               u16* __restrict__ dstH2, const float* __restrict__ kaux,
               const int M, const int N, const int K)
{
    __shared__ u16 As[128][64];
    __shared__ u16 Bs[128][64];
    __shared__ u16 As2[SPLIT ? 128 : 1][64];
    __shared__ u16 Bs2[SPLIT ? 128 : 1][64];

    const int tid  = threadIdx.x;
    const int w    = tid >> 6;
    const int lane = tid & 63;
    const int lg   = lane >> 4;
    const int lr   = lane & 15;
    const int wr   = w >> 1, wc = w & 1;
    const int m0   = blockIdx.y * 128, n0 = blockIdx.x * 128;

    const f32x4 zero = {0.f, 0.f, 0.f, 0.f};
    f32x4 acc[4][4];
#pragma unroll
    for (int i = 0; i < 4; ++i)
#pragma unroll
        for (int j = 0; j < 4; ++j) acc[i][j] = zero;

    const int srow = tid >> 3;
    const int scol = (tid & 7) * 8;
    const int ldr  = w << 3;

    for (int k0 = 0; k0 < K; k0 += 64) {
        __syncthreads();
#pragma unroll
        for (int i = 0; i < 4; ++i) {
            const size_t ga = (size_t)(m0 + i * 32 + srow) * K + k0 + scol;
            const size_t gb = (size_t)(n0 + i * 32 + srow) * K + k0 + scol;
            gload16(&Ah[ga], &As[i * 32 + ldr][0]);
            gload16(&Bh[gb], &Bs[i * 32 + ldr][0]);
            if constexpr (SPLIT) {
                gload16(&Al[ga], &As2[i * 32 + ldr][0]);
                gload16(&Bl[gb], &Bs2[i * 32 + ldr][0]);
            }
        }
        __syncthreads();
#pragma unroll
        for (int kk = 0; kk < 2; ++kk) {
            const int koff = kk * 32 + lg * 8;
            bf16x8 a_h[4], b_h[4];
#pragma unroll
            for (int f = 0; f < 4; ++f) {
                a_h[f] = *(const bf16x8*)&As[wr * 64 + f * 16 + lr][koff];
                b_h[f] = *(const bf16x8*)&Bs[wc * 64 + f * 16 + lr][koff];
            }
            if constexpr (SPLIT) {
                bf16x8 a_l[4], b_l[4];
#pragma unroll
                for (int f = 0; f < 4; ++f) {
                    a_l[f] = *(const bf16x8*)&As2[wr * 64 + f * 16 + lr][koff];
                    b_l[f] = *(const bf16x8*)&Bs2[wc * 64 + f * 16 + lr][koff];
                }
#pragma unroll
                for (int mf = 0; mf < 4; ++mf)
#pragma unroll
                    for (int nf = 0; nf < 4; ++nf) {
                        acc[mf][nf] = __builtin_amdgcn_mfma_f32_16x16x32_bf16(a_h[mf], b_h[nf], acc[mf][nf], 0, 0, 0);
                        acc[mf][nf] = __builtin_amdgcn_mfma_f32_16x16x32_bf16(a_l[mf], b_h[nf], acc[mf][nf], 0, 0, 0);
                        acc[mf][nf] = __builtin_amdgcn_mfma_f32_16x16x32_bf16(a_h[mf], b_l[nf], acc[mf][nf], 0, 0, 0);
                    }
            } else {
#pragma unroll
                for (int mf = 0; mf < 4; ++mf)
#pragma unroll
                    for (int nf = 0; nf < 4; ++nf)
                        acc[mf][nf] = __builtin_amdgcn_mfma_f32_16x16x32_bf16(a_h[mf], b_h[nf], acc[mf][nf], 0, 0, 0);
            }
        }
    }

#pragma unroll
    for (int mf = 0; mf < 4; ++mf)
#pragma unroll
        for (int nf = 0; nf < 4; ++nf)
#pragma unroll
            for (int j = 0; j < 4; ++j) {
                const int gm = m0 + wr * 64 + mf * 16 + lg * 4 + j;
                const int gn = n0 + wc * 64 + nf * 16 + lr;
                const float v = acc[mf][nf][j] + bias[gn];
                if constexpr (MODE == 0) {
                    const int bb = gm >> 10, t = gm & 1023;
                    const int c = gn >> 10, hh = (gn & 1023) >> 6, d = gn & 63;
                    const size_t idx = ((((size_t)bb * HH + hh) << 10) + t) * HDIM + d;
                    if (c == 0) dstH1[idx] = f2bf(v * 0.125f);
                    else { dstF[idx] = v; dstH2[idx] = f2bf(v); }
                } else if constexpr (MODE == 1) {
                    const int bb = gm >> 10, t = gm & 1023;
                    const int hh = gn >> 6, d = gn & 63;
                    const size_t idx = ((((size_t)bb * HH + hh) << 10) + t) * HDIM + d;
                    dstH1[idx] = f2bf(v + kaux[idx]);
                } else {
                    dstF[(size_t)gm * N + gn] = v;
                }
            }
}

// ---------------------------------------------------------------------------
// MFMA attention (round-3 structure, measured best: ~115 us).
// Block = one (b,h) x 64 q-rows; 4 waves x 16 rows each. 28 KB LDS ->
// ~5 blocks/CU. Pass 1: rowsums of exp(S) (S in accumulators only).
// Pass 2: recompute S, normalize, write attn, P via per-wave LDS round-trip,
// PV against kT tiles. ONLY change vs r3: kT staged with coalesced bf16x8
// loads from the pre-transposed k16T (was 256 scalar u16 loads per tile).
// A/B frag k-map: k = 8*(lane>>4)+i; C/D map: col=lane&15, row=4*(lane>>4)+reg.
// ---------------------------------------------------------------------------
__global__ __launch_bounds__(256)
void attn_mfma(const u16* __restrict__ qg, const u16* __restrict__ kTg,
               const u16* __restrict__ kpg,
               float* __restrict__ attn, u16* __restrict__ ch)
{
    __shared__ u16 kp_s[64][72];      // kv-tile of kp, row-major [kk][d]
    __shared__ u16 kT_s[64][72];      // kv-tile of k, transposed [d][kk]
    __shared__ u16 P_s[4][16][72];    // per-wave normalized P tile [q][kk]

    const int tid  = threadIdx.x;
    const int w    = tid >> 6;        // wave 0..3
    const int lane = tid & 63;
    const int lg   = lane >> 4;       // 0..3
    const int lr   = lane & 15;       // 0..15
    const int q0   = blockIdx.x * 64;
    const int h = blockIdx.y, b = blockIdx.z;
    const size_t hb = ((size_t)(b * HH + h)) << 16;    // head base (T*64 elems)

    bf16x8 qf0, qf1;
    {
        const size_t base = hb + (size_t)(q0 + w * 16 + lr) * HDIM + lg * 8;
        qf0 = *(const bf16x8*)&qg[base];
        qf1 = *(const bf16x8*)&qg[base + 32];
    }

    const int sr = tid >> 2;          // staging row 0..63
    const int sc = (tid & 3) * 8;     // staging col chunk

    // ---- pass 1: rowsums ----
    float rs[4] = {0.f, 0.f, 0.f, 0.f};
    for (int t = 0; t < TT / 64; ++t) {
        const size_t kvbase = hb + (size_t)(t * 64) * HDIM;
        __syncthreads();
        *(bf16x8*)&kp_s[sr][sc]      = *(const bf16x8*)&kpg[kvbase + sr * HDIM + sc];
        *(bf16x8*)&kp_s[sr][sc + 32] = *(const bf16x8*)&kpg[kvbase + sr * HDIM + sc + 32];
        __syncthreads();
#pragma unroll
        for (int ct = 0; ct < 4; ++ct) {
            f32x4 acc = {0.f, 0.f, 0.f, 0.f};
            const bf16x8 b0 = *(const bf16x8*)&kp_s[ct * 16 + lr][lg * 8];
            const bf16x8 b1 = *(const bf16x8*)&kp_s[ct * 16 + lr][lg * 8 + 32];
            acc = __builtin_amdgcn_mfma_f32_16x16x32_bf16(qf0, b0, acc, 0, 0, 0);
            acc = __builtin_amdgcn_mfma_f32_16x16x32_bf16(qf1, b1, acc, 0, 0, 0);
#pragma unroll
            for (int j = 0; j < 4; ++j) rs[j] += __expf(acc[j]);
        }
    }
#pragma unroll
    for (int off = 1; off < 16; off <<= 1) {
#pragma unroll
        for (int j = 0; j < 4; ++j) rs[j] += __shfl_xor(rs[j], off);
    }
    float ri[4];
#pragma unroll
    for (int j = 0; j < 4; ++j) ri[j] = 1.f / rs[j];

    // ---- pass 2: attn write + PV ----
    f32x4 cacc[4] = {{0,0,0,0},{0,0,0,0},{0,0,0,0},{0,0,0,0}};
    const size_t abase = ((((size_t)b * HH + h) << 10) + q0 + w * 16) << 10;

    for (int t = 0; t < TT / 64; ++t) {
        const size_t kvbase = hb + (size_t)(t * 64) * HDIM;
        __syncthreads();
        *(bf16x8*)&kp_s[sr][sc]      = *(const bf16x8*)&kpg[kvbase + sr * HDIM + sc];
        *(bf16x8*)&kp_s[sr][sc + 32] = *(const bf16x8*)&kpg[kvbase + sr * HDIM + sc + 32];
        // kT tile: row d holds kv t*64..t*64+63 of dim d  (coalesced vector loads)
        *(bf16x8*)&kT_s[sr][sc]      = *(const bf16x8*)&kTg[hb + (size_t)sr * TT + t * 64 + sc];
        *(bf16x8*)&kT_s[sr][sc + 32] = *(const bf16x8*)&kTg[hb + (size_t)sr * TT + t * 64 + sc + 32];
        __syncthreads();
#pragma unroll
        for (int ct = 0; ct < 4; ++ct) {
            f32x4 acc = {0.f, 0.f, 0.f, 0.f};
            const bf16x8 b0 = *(const bf16x8*)&kp_s[ct * 16 + lr][lg * 8];
            const bf16x8 b1 = *(const bf16x8*)&kp_s[ct * 16 + lr][lg * 8 + 32];
            acc = __builtin_amdgcn_mfma_f32_16x16x32_bf16(qf0, b0, acc, 0, 0, 0);
            acc = __builtin_amdgcn_mfma_f32_16x16x32_bf16(qf1, b1, acc, 0, 0, 0);
            const int col = t * 64 + ct * 16 + lr;
#pragma unroll
            for (int j = 0; j < 4; ++j) {
                const float p = __expf(acc[j]) * ri[j];
                attn[abase + (size_t)(lg * 4 + j) * TT + col] = p;
                P_s[w][lg * 4 + j][ct * 16 + lr] = f2bf(p);
            }
        }
        asm volatile("s_waitcnt lgkmcnt(0)" ::: "memory");   // P_s write->read, same wave
        const bf16x8 pa0 = *(const bf16x8*)&P_s[w][lr][lg * 8];
        const bf16x8 pa1 = *(const bf16x8*)&P_s[w][lr][lg * 8 + 32];
#pragma unroll
        for (int dt = 0; dt < 4; ++dt) {
            const bf16x8 kb0 = *(const bf16x8*)&kT_s[dt * 16 + lr][lg * 8];
            const bf16x8 kb1 = *(const bf16x8*)&kT_s[dt * 16 + lr][lg * 8 + 32];
            cacc[dt] = __builtin_amdgcn_mfma_f32_16x16x32_bf16(pa0, kb0, cacc[dt], 0, 0, 0);
            cacc[dt] = __builtin_amdgcn_mfma_f32_16x16x32_bf16(pa1, kb1, cacc[dt], 0, 0, 0);
        }
    }

    // ctx -> bf16 [B][T][H*64]
#pragma unroll
    for (int dt = 0; dt < 4; ++dt)
#pragma unroll
        for (int j = 0; j < 4; ++j) {
            const int qr = q0 + w * 16 + lg * 4 + j;
            ch[(((size_t)b << 10) + qr) * DD + h * HDIM + dt * 16 + lr] = f2bf(cacc[dt][j]);
        }
}

extern "C" void kernel_launch(void* const* d_in, const int* in_sizes, int n_in,
                              void* d_out, int out_size, void* d_ws, size_t ws_size,
                              hipStream_t stream)
{
    const float* x  = (const float*)d_in[0];
    const float* pe = (const float*)d_in[1];
    const float* Wc = (const float*)d_in[2];
    const float* bc = (const float*)d_in[3];
    const float* Wp = (const float*)d_in[4];
    const float* bp = (const float*)d_in[5];
    const float* Wo = (const float*)d_in[6];
    const float* bo = (const float*)d_in[7];

    float* out  = (float*)d_out;                         // [B][T][D]
    float* attn = out + (size_t)MM * DD;                 // [B][H][T][T]

    // 64 MB workspace layout (in-order stream => safe region reuse)
    char* ws = (char*)d_ws;
    float* kf32 = (float*)(ws);                          // [0,16M)   k fp32
    u16* q16  = (u16*)(ws + ((size_t)16 << 20));         // [16,24M)
    u16* k16  = (u16*)(ws + ((size_t)24 << 20));         // [24,32M)
    u16* kp16 = (u16*)(ws + ((size_t)32 << 20));         // [32,40M)
    u16* k16T = (u16*)(ws + ((size_t)56 << 20));         // [56,64M)  k transposed
    u16* xh  = (u16*)(ws + ((size_t)40 << 20));          // 8MB
    u16* xl  = (u16*)(ws + ((size_t)48 << 20));          // 8MB
    u16* Wch = (u16*)(ws + ((size_t)56 << 20));          // 4MB (k16T area, dead before ktrans)
    u16* Wcl = (u16*)(ws + ((size_t)60 << 20));          // 4MB
    u16* peh = xh, *pel = xl;                            // after cqk
    u16* Wph = (u16*)(ws + ((size_t)24 << 20));          // k16 area, dead after ktrans
    u16* Wpl = (u16*)(ws + ((size_t)26 << 20));
    u16* chh = xh;                                       // ctx bf16, after pk
    u16* Woh = (u16*)(ws + ((size_t)48 << 20));          // 2MB (xl dead)

    // 1) splits for cqk
    split_kernel<<<4096, 256, 0, stream>>>(x, xh, xl);
    split_kernel<<<2048, 256, 0, stream>>>(Wc, Wch, Wcl);
    // 2) cqk = x @ Wc^T + bc -> q16 (scaled), kf32, k16
    gemm_mfma<true, 0><<<dim3(16, 32), 256, 0, stream>>>(
        xh, xl, Wch, Wcl, bc, kf32, q16, k16, nullptr, MM, 2048, DD);
    // 3) k16T = transpose(k16)  (overwrites Wc split -- dead after gemm)
    ktrans_kernel<<<dim3(16, HH, BB), 256, 0, stream>>>(k16, k16T);
    // 4) splits for pk (Wp split into k16's region -- k16 dead after ktrans)
    split_kernel<<<4096, 256, 0, stream>>>(pe, peh, pel);
    split_kernel<<<1024, 256, 0, stream>>>(Wp, Wph, Wpl);
    // 5) pk = pe @ Wp^T + bp; kp16 = bf16(pk + k)
    gemm_mfma<true, 1><<<dim3(8, 32), 256, 0, stream>>>(
        peh, pel, Wph, Wpl, bp, nullptr, kp16, nullptr, kf32, MM, 1024, DD);
    // 6) attention: attn f32 + ctx bf16
    attn_mfma<<<dim3(TT / 64, HH, BB), 256, 0, stream>>>(
        q16, k16T, kp16, attn, chh);
    // 7) split Wo (hi only), out = ctx @ Wo^T + bo
    split_kernel<<<1024, 256, 0, stream>>>(Wo, Woh, nullptr);
    gemm_mfma<false, 2><<<dim3(8, 32), 256, 0, stream>>>(
        chh, nullptr, Woh, nullptr, bo, out, nullptr, nullptr, nullptr, MM, 1024, DD);
}

// Round 9
// 209.432 us; speedup vs baseline: 1.9259x; 1.1946x over previous
//
#include <hip/hip_runtime.h>
#include <hip/hip_bf16.h>

// Problem constants (fixed by the reference)
#define BB 4
#define TT 1024
#define DD 1024
#define HH 16
#define HDIM 64
#define MM (BB*TT)          // 4096

typedef unsigned short u16;
typedef __attribute__((ext_vector_type(8))) short bf16x8;     // 8 bf16 = 4 VGPRs
typedef __attribute__((ext_vector_type(8))) _Float16 f16x8;   // 8 fp16 = 4 VGPRs
typedef __attribute__((ext_vector_type(4))) float f32x4;
typedef __attribute__((ext_vector_type(4))) unsigned short u16x4;

__device__ __forceinline__ u16 f2bf(float f) {
    union { float f; unsigned u; } v; v.f = f;
    return (u16)((v.u + 0x7fffu + ((v.u >> 16) & 1u)) >> 16);   // RNE
}
__device__ __forceinline__ float bf2f(u16 h) {
    union { unsigned u; float f; } v; v.u = ((unsigned)h) << 16; return v.f;
}
__device__ __forceinline__ u16 f2h(float f) {
    union { _Float16 h; u16 u; } v; v.h = (_Float16)f;          // v_cvt_f16_f32 RNE
    return v.u;
}

// async global->LDS, 16B per lane; lds dest = wave-uniform base + lane*16
__device__ __forceinline__ void gload16(const void* g, void* l) {
    __builtin_amdgcn_global_load_lds(
        (const __attribute__((address_space(1))) unsigned int*)g,
        (__attribute__((address_space(3))) unsigned int*)l, 16, 0, 0);
}

// f32 -> fp16 (TO_FP16=true) or bf16 (false), 4 elems/thread
template<bool TO_FP16>
__global__ __launch_bounds__(256)
void cvt_kernel(const float* __restrict__ src, u16* __restrict__ dst)
{
    const size_t i = ((size_t)blockIdx.x * 256 + threadIdx.x) * 4;
    const float4 v = *(const float4*)&src[i];
    u16x4 o;
    if constexpr (TO_FP16) {
        o[0] = f2h(v.x); o[1] = f2h(v.y); o[2] = f2h(v.z); o[3] = f2h(v.w);
    } else {
        o[0] = f2bf(v.x); o[1] = f2bf(v.y); o[2] = f2bf(v.z); o[3] = f2bf(v.w);
    }
    *(u16x4*)&dst[i] = o;
}

// k16 [b][h][t][64] -> k16T [b][h][d][1024]   (per-head 64-col transpose)
__global__ __launch_bounds__(256)
void ktrans_kernel(const u16* __restrict__ k16, u16* __restrict__ k16T)
{
    __shared__ u16 tmp[64][72];
    const int tc = blockIdx.x, h = blockIdx.y, b = blockIdx.z;
    const size_t hb = ((size_t)(b * HH + h)) << 16;
    const int tid = threadIdx.x;
    const int sr = tid >> 2, sc = (tid & 3) * 8;
    *(bf16x8*)&tmp[sr][sc]      = *(const bf16x8*)&k16[hb + (size_t)(tc * 64 + sr) * HDIM + sc];
    *(bf16x8*)&tmp[sr][sc + 32] = *(const bf16x8*)&k16[hb + (size_t)(tc * 64 + sr) * HDIM + sc + 32];
    __syncthreads();
#pragma unroll
    for (int half = 0; half < 2; ++half) {
        bf16x8 v;
#pragma unroll
        for (int j = 0; j < 8; ++j) v[j] = (short)tmp[sc + half * 32 + j][sr];
        *(bf16x8*)&k16T[hb + (size_t)sr * TT + tc * 64 + sc + half * 32] = v;
    }
}

// ---------------------------------------------------------------------------
// MFMA GEMM: C = A @ B^T + bias.  A: [M][K], B: [N][K], both u16-encoded
// (fp16 if FP16 else bf16). 128x128 tile, BK=64, 4 waves, gload16 staging.
// MODE 0 (cqk, N=2048): n<1024 -> q16 = bf16(v*0.125); else kf32 + k16 (bf16)
// MODE 1 (pk):          kp16 = bf16(v + kaux[idx])  (head-scatter layout)
// MODE 2 (out):         dstF row-major f32
// ---------------------------------------------------------------------------
template<bool FP16, int MODE>
__global__ __launch_bounds__(256)
void gemm_mfma(const u16* __restrict__ Ah, const u16* __restrict__ Bh,
               const float* __restrict__ bias,
               float* __restrict__ dstF, u16* __restrict__ dstH1,
               u16* __restrict__ dstH2, const float* __restrict__ kaux,
               const int M, const int N, const int K)
{
    __shared__ u16 As[128][64];
    __shared__ u16 Bs[128][64];

    const int tid  = threadIdx.x;
    const int w    = tid >> 6;
    const int lane = tid & 63;
    const int lg   = lane >> 4;
    const int lr   = lane & 15;
    const int wr   = w >> 1, wc = w & 1;
    const int m0   = blockIdx.y * 128, n0 = blockIdx.x * 128;

    const f32x4 zero = {0.f, 0.f, 0.f, 0.f};
    f32x4 acc[4][4];
#pragma unroll
    for (int i = 0; i < 4; ++i)
#pragma unroll
        for (int j = 0; j < 4; ++j) acc[i][j] = zero;

    const int srow = tid >> 3;
    const int scol = (tid & 7) * 8;
    const int ldr  = w << 3;

    for (int k0 = 0; k0 < K; k0 += 64) {
        __syncthreads();
#pragma unroll
        for (int i = 0; i < 4; ++i) {
            const size_t ga = (size_t)(m0 + i * 32 + srow) * K + k0 + scol;
            const size_t gb = (size_t)(n0 + i * 32 + srow) * K + k0 + scol;
            gload16(&Ah[ga], &As[i * 32 + ldr][0]);
            gload16(&Bh[gb], &Bs[i * 32 + ldr][0]);
        }
        __syncthreads();
#pragma unroll
        for (int kk = 0; kk < 2; ++kk) {
            const int koff = kk * 32 + lg * 8;
#pragma unroll
            for (int mf = 0; mf < 4; ++mf) {
#pragma unroll
                for (int nf = 0; nf < 4; ++nf) {
                    if constexpr (FP16) {
                        const f16x8 a = *(const f16x8*)&As[wr * 64 + mf * 16 + lr][koff];
                        const f16x8 b = *(const f16x8*)&Bs[wc * 64 + nf * 16 + lr][koff];
                        acc[mf][nf] = __builtin_amdgcn_mfma_f32_16x16x32_f16(a, b, acc[mf][nf], 0, 0, 0);
                    } else {
                        const bf16x8 a = *(const bf16x8*)&As[wr * 64 + mf * 16 + lr][koff];
                        const bf16x8 b = *(const bf16x8*)&Bs[wc * 64 + nf * 16 + lr][koff];
                        acc[mf][nf] = __builtin_amdgcn_mfma_f32_16x16x32_bf16(a, b, acc[mf][nf], 0, 0, 0);
                    }
                }
            }
        }
    }

    // epilogue: C/D map col=lane&15, row=4*(lane>>4)+reg (verified)
#pragma unroll
    for (int mf = 0; mf < 4; ++mf)
#pragma unroll
        for (int nf = 0; nf < 4; ++nf)
#pragma unroll
            for (int j = 0; j < 4; ++j) {
                const int gm = m0 + wr * 64 + mf * 16 + lg * 4 + j;
                const int gn = n0 + wc * 64 + nf * 16 + lr;
                const float v = acc[mf][nf][j] + bias[gn];
                if constexpr (MODE == 0) {
                    const int bb = gm >> 10, t = gm & 1023;
                    const int c = gn >> 10, hh = (gn & 1023) >> 6, d = gn & 63;
                    const size_t idx = ((((size_t)bb * HH + hh) << 10) + t) * HDIM + d;
                    if (c == 0) dstH1[idx] = f2bf(v * 0.125f);       // q, pre-scaled
                    else { dstF[idx] = v; dstH2[idx] = f2bf(v); }    // k fp32 + bf16
                } else if constexpr (MODE == 1) {
                    const int bb = gm >> 10, t = gm & 1023;
                    const int hh = gn >> 6, d = gn & 63;
                    const size_t idx = ((((size_t)bb * HH + hh) << 10) + t) * HDIM + d;
                    dstH1[idx] = f2bf(v + kaux[idx]);                // kp = pk + k
                } else {
                    dstF[(size_t)gm * N + gn] = v;
                }
            }
}

// ---------------------------------------------------------------------------
// MFMA attention (round-8 structure, measured best). Unchanged.
// ---------------------------------------------------------------------------
__global__ __launch_bounds__(256)
void attn_mfma(const u16* __restrict__ qg, const u16* __restrict__ kTg,
               const u16* __restrict__ kpg,
               float* __restrict__ attn, u16* __restrict__ ch)
{
    __shared__ u16 kp_s[64][72];      // kv-tile of kp, row-major [kk][d]
    __shared__ u16 kT_s[64][72];      // kv-tile of k, transposed [d][kk]
    __shared__ u16 P_s[4][16][72];    // per-wave normalized P tile [q][kk]

    const int tid  = threadIdx.x;
    const int w    = tid >> 6;        // wave 0..3
    const int lane = tid & 63;
    const int lg   = lane >> 4;       // 0..3
    const int lr   = lane & 15;       // 0..15
    const int q0   = blockIdx.x * 64;
    const int h = blockIdx.y, b = blockIdx.z;
    const size_t hb = ((size_t)(b * HH + h)) << 16;    // head base (T*64 elems)

    bf16x8 qf0, qf1;
    {
        const size_t base = hb + (size_t)(q0 + w * 16 + lr) * HDIM + lg * 8;
        qf0 = *(const bf16x8*)&qg[base];
        qf1 = *(const bf16x8*)&qg[base + 32];
    }

    const int sr = tid >> 2;          // staging row 0..63
    const int sc = (tid & 3) * 8;     // staging col chunk

    // ---- pass 1: rowsums ----
    float rs[4] = {0.f, 0.f, 0.f, 0.f};
    for (int t = 0; t < TT / 64; ++t) {
        const size_t kvbase = hb + (size_t)(t * 64) * HDIM;
        __syncthreads();
        *(bf16x8*)&kp_s[sr][sc]      = *(const bf16x8*)&kpg[kvbase + sr * HDIM + sc];
        *(bf16x8*)&kp_s[sr][sc + 32] = *(const bf16x8*)&kpg[kvbase + sr * HDIM + sc + 32];
        __syncthreads();
#pragma unroll
        for (int ct = 0; ct < 4; ++ct) {
            f32x4 acc = {0.f, 0.f, 0.f, 0.f};
            const bf16x8 b0 = *(const bf16x8*)&kp_s[ct * 16 + lr][lg * 8];
            const bf16x8 b1 = *(const bf16x8*)&kp_s[ct * 16 + lr][lg * 8 + 32];
            acc = __builtin_amdgcn_mfma_f32_16x16x32_bf16(qf0, b0, acc, 0, 0, 0);
            acc = __builtin_amdgcn_mfma_f32_16x16x32_bf16(qf1, b1, acc, 0, 0, 0);
#pragma unroll
            for (int j = 0; j < 4; ++j) rs[j] += __expf(acc[j]);
        }
    }
#pragma unroll
    for (int off = 1; off < 16; off <<= 1) {
#pragma unroll
        for (int j = 0; j < 4; ++j) rs[j] += __shfl_xor(rs[j], off);
    }
    float ri[4];
#pragma unroll
    for (int j = 0; j < 4; ++j) ri[j] = 1.f / rs[j];

    // ---- pass 2: attn write + PV ----
    f32x4 cacc[4] = {{0,0,0,0},{0,0,0,0},{0,0,0,0},{0,0,0,0}};
    const size_t abase = ((((size_t)b * HH + h) << 10) + q0 + w * 16) << 10;

    for (int t = 0; t < TT / 64; ++t) {
        const size_t kvbase = hb + (size_t)(t * 64) * HDIM;
        __syncthreads();
        *(bf16x8*)&kp_s[sr][sc]      = *(const bf16x8*)&kpg[kvbase + sr * HDIM + sc];
        *(bf16x8*)&kp_s[sr][sc + 32] = *(const bf16x8*)&kpg[kvbase + sr * HDIM + sc + 32];
        // kT tile: row d holds kv t*64..t*64+63 of dim d  (coalesced vector loads)
        *(bf16x8*)&kT_s[sr][sc]      = *(const bf16x8*)&kTg[hb + (size_t)sr * TT + t * 64 + sc];
        *(bf16x8*)&kT_s[sr][sc + 32] = *(const bf16x8*)&kTg[hb + (size_t)sr * TT + t * 64 + sc + 32];
        __syncthreads();
#pragma unroll
        for (int ct = 0; ct < 4; ++ct) {
            f32x4 acc = {0.f, 0.f, 0.f, 0.f};
            const bf16x8 b0 = *(const bf16x8*)&kp_s[ct * 16 + lr][lg * 8];
            const bf16x8 b1 = *(const bf16x8*)&kp_s[ct * 16 + lr][lg * 8 + 32];
            acc = __builtin_amdgcn_mfma_f32_16x16x32_bf16(qf0, b0, acc, 0, 0, 0);
            acc = __builtin_amdgcn_mfma_f32_16x16x32_bf16(qf1, b1, acc, 0, 0, 0);
            const int col = t * 64 + ct * 16 + lr;
#pragma unroll
            for (int j = 0; j < 4; ++j) {
                const float p = __expf(acc[j]) * ri[j];
                attn[abase + (size_t)(lg * 4 + j) * TT + col] = p;
                P_s[w][lg * 4 + j][ct * 16 + lr] = f2bf(p);
            }
        }
        asm volatile("s_waitcnt lgkmcnt(0)" ::: "memory");   // P_s write->read, same wave
        const bf16x8 pa0 = *(const bf16x8*)&P_s[w][lr][lg * 8];
        const bf16x8 pa1 = *(const bf16x8*)&P_s[w][lr][lg * 8 + 32];
#pragma unroll
        for (int dt = 0; dt < 4; ++dt) {
            const bf16x8 kb0 = *(const bf16x8*)&kT_s[dt * 16 + lr][lg * 8];
            const bf16x8 kb1 = *(const bf16x8*)&kT_s[dt * 16 + lr][lg * 8 + 32];
            cacc[dt] = __builtin_amdgcn_mfma_f32_16x16x32_bf16(pa0, kb0, cacc[dt], 0, 0, 0);
            cacc[dt] = __builtin_amdgcn_mfma_f32_16x16x32_bf16(pa1, kb1, cacc[dt], 0, 0, 0);
        }
    }

    // ctx -> bf16 [B][T][H*64]
#pragma unroll
    for (int dt = 0; dt < 4; ++dt)
#pragma unroll
        for (int j = 0; j < 4; ++j) {
            const int qr = q0 + w * 16 + lg * 4 + j;
            ch[(((size_t)b << 10) + qr) * DD + h * HDIM + dt * 16 + lr] = f2bf(cacc[dt][j]);
        }
}

extern "C" void kernel_launch(void* const* d_in, const int* in_sizes, int n_in,
                              void* d_out, int out_size, void* d_ws, size_t ws_size,
                              hipStream_t stream)
{
    const float* x  = (const float*)d_in[0];
    const float* pe = (const float*)d_in[1];
    const float* Wc = (const float*)d_in[2];
    const float* bc = (const float*)d_in[3];
    const float* Wp = (const float*)d_in[4];
    const float* bp = (const float*)d_in[5];
    const float* Wo = (const float*)d_in[6];
    const float* bo = (const float*)d_in[7];

    float* out  = (float*)d_out;                         // [B][T][D]
    float* attn = out + (size_t)MM * DD;                 // [B][H][T][T]

    // 64 MB workspace layout (in-order stream => safe region reuse)
    char* ws = (char*)d_ws;
    float* kf32 = (float*)(ws);                          // [0,16M)   k fp32
    u16* q16  = (u16*)(ws + ((size_t)16 << 20));         // [16,24M)  bf16
    u16* k16  = (u16*)(ws + ((size_t)24 << 20));         // [24,32M)  bf16
    u16* kp16 = (u16*)(ws + ((size_t)32 << 20));         // [32,40M)  bf16
    u16* x16  = (u16*)(ws + ((size_t)40 << 20));         // [40,48M)  fp16 x / pe / ctx (phased)
    u16* Wc16 = (u16*)(ws + ((size_t)56 << 20));         // [56,60M)  fp16, dead before ktrans
    u16* k16T = (u16*)(ws + ((size_t)56 << 20));         // [56,64M)  bf16 k^T (after cqk)
    u16* pe16 = x16;                                     // x dead after cqk
    u16* Wp16 = (u16*)(ws + ((size_t)24 << 20));         // k16 area, dead after ktrans
    u16* chh  = x16;                                     // ctx bf16, after pk (pe dead)
    u16* Wo16 = (u16*)(ws + ((size_t)48 << 20));         // [48,50M)  bf16

    // 1) conversions for cqk
    cvt_kernel<true><<<4096, 256, 0, stream>>>(x, x16);
    cvt_kernel<true><<<2048, 256, 0, stream>>>(Wc, Wc16);
    // 2) cqk = x @ Wc^T + bc  (fp16 MFMA) -> q16 (scaled bf16), kf32, k16
    gemm_mfma<true, 0><<<dim3(16, 32), 256, 0, stream>>>(
        x16, Wc16, bc, kf32, q16, k16, nullptr, MM, 2048, DD);
    // 3) k16T = transpose(k16)  (overwrites Wc16 -- dead after gemm)
    ktrans_kernel<<<dim3(16, HH, BB), 256, 0, stream>>>(k16, k16T);
    // 4) conversions for pk (Wp into k16's region -- k16 dead after ktrans)
    cvt_kernel<true><<<4096, 256, 0, stream>>>(pe, pe16);
    cvt_kernel<true><<<1024, 256, 0, stream>>>(Wp, Wp16);
    // 5) pk = pe @ Wp^T + bp (fp16 MFMA); kp16 = bf16(pk + k)
    gemm_mfma<true, 1><<<dim3(8, 32), 256, 0, stream>>>(
        pe16, Wp16, bp, nullptr, kp16, nullptr, kf32, MM, 1024, DD);
    // 6) attention: attn f32 + ctx bf16
    attn_mfma<<<dim3(TT / 64, HH, BB), 256, 0, stream>>>(
        q16, k16T, kp16, attn, chh);
    // 7) Wo -> bf16; out = ctx @ Wo^T + bo (bf16 MFMA)
    cvt_kernel<false><<<1024, 256, 0, stream>>>(Wo, Wo16);
    gemm_mfma<false, 2><<<dim3(8, 32), 256, 0, stream>>>(
        chh, Wo16, bo, out, nullptr, nullptr, nullptr, MM, 1024, DD);
}